// Round 7
// baseline (2426.233 us; speedup 1.0000x reference)
//
#include <hip/hip_runtime.h>
#include <math.h>

#define CDIM 256
#define HDIM 512
#define KCLS 20
#define MAXSEG 8

// ---------------------------------------------------------------------------
// DPP fused shuffle-add: 16-lane-group sum in 4 VALU steps (no LDS pipe).
//   0xB1 = quad_perm(1,0,3,2)  -> xor 1
//   0x4E = quad_perm(2,3,0,1)  -> xor 2
//   0x141 = row_half_mirror    -> pairs quads within 8
//   0x140 = row_mirror         -> pairs 8-groups within 16
// ---------------------------------------------------------------------------
template <int CTRL>
__device__ __forceinline__ float dpp_add16(float v) {
  int s = __builtin_amdgcn_update_dpp(0, __float_as_int(v), CTRL, 0xF, 0xF, 1);
  return v + __int_as_float(s);
}
__device__ __forceinline__ float4 red16(float4 v) {
  v.x = dpp_add16<0xB1>(v.x);  v.y = dpp_add16<0xB1>(v.y);
  v.z = dpp_add16<0xB1>(v.z);  v.w = dpp_add16<0xB1>(v.w);
  v.x = dpp_add16<0x4E>(v.x);  v.y = dpp_add16<0x4E>(v.y);
  v.z = dpp_add16<0x4E>(v.z);  v.w = dpp_add16<0x4E>(v.w);
  v.x = dpp_add16<0x141>(v.x); v.y = dpp_add16<0x141>(v.y);
  v.z = dpp_add16<0x141>(v.z); v.w = dpp_add16<0x141>(v.w);
  v.x = dpp_add16<0x140>(v.x); v.y = dpp_add16<0x140>(v.y);
  v.z = dpp_add16<0x140>(v.z); v.w = dpp_add16<0x140>(v.w);
  return v;
}

// ---------------------------------------------------------------------------
// Fused single pass over feat. Thread-per-row, NO LDS, NO barriers.
// Wave-block = 64 consecutive rows (lane = row). Per float4-column step:
//   head : acc[20] += f · W_head[k][c4]   (W via wave-uniform scalar loads)
//   colsum: red16(f) -> 16-row-group partial; lane (l15==c4&15) accumulates
//           colacc[c4>>4] (static q index); flush on segment change (atomics).
// Boundary / tail blocks take a masked slow path with immediate atomics.
// ---------------------------------------------------------------------------
__global__ __launch_bounds__(256, 6) void fused_stream_kernel(
    const float* __restrict__ feat, const int* __restrict__ offset,
    const float* __restrict__ W_head, const float* __restrict__ b_head,
    float* __restrict__ sums, float* __restrict__ out, int n, int nseg) {
  int t = threadIdx.x;
  int lane = t & 63;
  int wv = t >> 6;
  int l15 = lane & 15;

  long nwb = ((long)n + 63) >> 6;
  long gwaves = (long)gridDim.x * 4;
  long wid = (long)blockIdx.x * 4 + wv;

  int off[MAXSEG];
#pragma unroll
  for (int q = 0; q < MAXSEG; ++q) off[q] = (q < nseg) ? offset[q] : 0x7fffffff;

  float bh[KCLS];
#pragma unroll
  for (int k = 0; k < KCLS; ++k) bh[k] = b_head[k];  // uniform -> SGPR

  float4 colacc[4];
#pragma unroll
  for (int q = 0; q < 4; ++q) colacc[q] = make_float4(0.f, 0.f, 0.f, 0.f);
  int cur_seg = -1;

  auto flush = [&]() {
    if (cur_seg >= 0) {
#pragma unroll
      for (int q = 0; q < 4; ++q) {
        float* d = &sums[cur_seg * CDIM + (q * 16 + l15) * 4];
        atomicAdd(d + 0, colacc[q].x);
        atomicAdd(d + 1, colacc[q].y);
        atomicAdd(d + 2, colacc[q].z);
        atomicAdd(d + 3, colacc[q].w);
        colacc[q] = make_float4(0.f, 0.f, 0.f, 0.f);
      }
    }
  };

  for (long wb = wid; wb < nwb; wb += gwaves) {
    long r0 = wb << 6;
    long r = r0 + lane;
    bool valid = (r < (long)n);
    long rc = valid ? r : (long)(n - 1);
    long rlast = ((r0 + 63) < (long)n) ? (r0 + 63) : (long)(n - 1);

    int s0 = 0, s1 = 0, myseg = 0;
#pragma unroll
    for (int q = 0; q < MAXSEG - 1; ++q) {
      s0 += (r0 >= off[q]) ? 1 : 0;
      s1 += (rlast >= off[q]) ? 1 : 0;
      myseg += (rc >= off[q]) ? 1 : 0;
    }

    const float4* rowp = (const float4*)(feat + rc * CDIM);
    float acc[KCLS];
#pragma unroll
    for (int k = 0; k < KCLS; ++k) acc[k] = bh[k];

    bool fast = (s0 == s1) && ((r0 + 64) <= (long)n);
    if (fast) {
      if (s0 != cur_seg) { flush(); cur_seg = s0; }
#pragma unroll
      for (int q = 0; q < 4; ++q) {        // static q -> colacc[q] in registers
#pragma unroll 4
        for (int c16 = 0; c16 < 16; ++c16) {
          int c4 = q * 16 + c16;
          float4 f = rowp[c4];
          // ---- head ----
#pragma unroll
          for (int k = 0; k < KCLS; ++k) {
            const float* w = W_head + k * CDIM + c4 * 4;  // uniform -> s_load
            acc[k] = fmaf(f.x, w[0], acc[k]);
            acc[k] = fmaf(f.y, w[1], acc[k]);
            acc[k] = fmaf(f.z, w[2], acc[k]);
            acc[k] = fmaf(f.w, w[3], acc[k]);
          }
          // ---- colsum ----
          float4 g = red16(f);
          bool take = (l15 == c16);
          colacc[q].x += take ? g.x : 0.f;
          colacc[q].y += take ? g.y : 0.f;
          colacc[q].z += take ? g.z : 0.f;
          colacc[q].w += take ? g.w : 0.f;
        }
      }
    } else {
      // boundary / tail block: masked reduces, immediate atomics (rare)
      for (int c4 = 0; c4 < 64; ++c4) {
        float4 f = rowp[c4];
#pragma unroll
        for (int k = 0; k < KCLS; ++k) {
          const float* w = W_head + k * CDIM + c4 * 4;
          acc[k] = fmaf(f.x, w[0], acc[k]);
          acc[k] = fmaf(f.y, w[1], acc[k]);
          acc[k] = fmaf(f.z, w[2], acc[k]);
          acc[k] = fmaf(f.w, w[3], acc[k]);
        }
        for (int s = s0; s <= s1; ++s) {
          bool m = valid && (myseg == s);
          float4 g;
          g.x = m ? f.x : 0.f; g.y = m ? f.y : 0.f;
          g.z = m ? f.z : 0.f; g.w = m ? f.w : 0.f;
          g = red16(g);
          if (l15 == (c4 & 15)) {
            float* d = &sums[s * CDIM + c4 * 4];
            atomicAdd(d + 0, g.x);
            atomicAdd(d + 1, g.y);
            atomicAdd(d + 2, g.z);
            atomicAdd(d + 3, g.w);
          }
        }
      }
    }
    // ---- store head row (20 floats = 5 float4, 16B-aligned: 80B rows) ----
    if (valid) {
      float4* orow = (float4*)(out + r * KCLS);
      orow[0] = make_float4(acc[0], acc[1], acc[2], acc[3]);
      orow[1] = make_float4(acc[4], acc[5], acc[6], acc[7]);
      orow[2] = make_float4(acc[8], acc[9], acc[10], acc[11]);
      orow[3] = make_float4(acc[12], acc[13], acc[14], acc[15]);
      orow[4] = make_float4(acc[16], acc[17], acc[18], acc[19]);
    }
  }
  flush();
}

// ---------------------------------------------------------------------------
// L1: h[s][j], wave-task = gate column j. lane = (seg, c-chunk); coalesced
// W_ih float4 rows; 3-step shfl_xor reduce within 8-lane seg groups.
// ---------------------------------------------------------------------------
__global__ __launch_bounds__(256) void lstm_h_kernel(
    const float* __restrict__ sums, const int* __restrict__ offset,
    const float* __restrict__ W_ih, const float* __restrict__ b_ih,
    const float* __restrict__ b_hh, float* __restrict__ h, int nseg) {
  __shared__ float pooled[MAXSEG * CDIM];
  int t = threadIdx.x;
  {
    int prev = 0;
    for (int s = 0; s < MAXSEG; ++s) {
      int cur = (s < nseg) ? offset[s] : prev;
      float cnt = (float)(cur - prev);
      float inv = (cnt > 0.f) ? 1.f / cnt : 0.f;
      pooled[s * CDIM + t] = sums[s * CDIM + t] * inv;
      prev = cur;
    }
  }
  __syncthreads();

  int wv = t >> 6, l = t & 63;
  int j = (int)blockIdx.x * 4 + wv;
  int s = l >> 3, ch = l & 7;

  const float4* Wi4 = (const float4*)(W_ih + (size_t)(0 * HDIM + j) * CDIM);
  const float4* Wg4 = (const float4*)(W_ih + (size_t)(2 * HDIM + j) * CDIM);
  const float4* Wo4 = (const float4*)(W_ih + (size_t)(3 * HDIM + j) * CDIM);
  const float4* p4 = (const float4*)(pooled + s * CDIM);

  float di = 0.f, dg = 0.f, dd = 0.f;
#pragma unroll
  for (int i = 0; i < 8; ++i) {
    int c4 = ch * 8 + i;
    float4 p = p4[c4];
    float4 wi = Wi4[c4], wg = Wg4[c4], wo = Wo4[c4];
    di = fmaf(p.x, wi.x, di); di = fmaf(p.y, wi.y, di);
    di = fmaf(p.z, wi.z, di); di = fmaf(p.w, wi.w, di);
    dg = fmaf(p.x, wg.x, dg); dg = fmaf(p.y, wg.y, dg);
    dg = fmaf(p.z, wg.z, dg); dg = fmaf(p.w, wg.w, dg);
    dd = fmaf(p.x, wo.x, dd); dd = fmaf(p.y, wo.y, dd);
    dd = fmaf(p.z, wo.z, dd); dd = fmaf(p.w, wo.w, dd);
  }
#pragma unroll
  for (int m = 1; m < 8; m <<= 1) {
    di += __shfl_xor(di, m);
    dg += __shfl_xor(dg, m);
    dd += __shfl_xor(dd, m);
  }
  if (ch == 0 && s < nseg) {
    di += b_ih[j] + b_hh[j];
    dg += b_ih[2 * HDIM + j] + b_hh[2 * HDIM + j];
    dd += b_ih[3 * HDIM + j] + b_hh[3 * HDIM + j];
    float ig = 1.f / (1.f + expf(-di));
    float gg = tanhf(dg);
    float og = 1.f / (1.f + expf(-dd));
    h[(size_t)s * HDIM + j] = og * tanhf(ig * gg);
  }
}

// ---------------------------------------------------------------------------
// L2: ctx[s][col] = b_proj[col] + h[s]·W_proj[col].
// ---------------------------------------------------------------------------
__global__ __launch_bounds__(256) void ctx_kernel(
    const float* __restrict__ h, const float* __restrict__ W_proj,
    const float* __restrict__ b_proj, float* __restrict__ ctx, int nseg) {
  __shared__ float hs[MAXSEG * HDIM];
  int t = threadIdx.x;
  {
    const float4* hsrc = (const float4*)h;
    float4* hdst = (float4*)hs;
#pragma unroll
    for (int i = 0; i < 4; ++i) hdst[i * 256 + t] = hsrc[i * 256 + t];
  }
  __syncthreads();

  int wv = t >> 6, l = t & 63;
  int col = (int)blockIdx.x * 4 + wv;
  int s = l >> 3, ch = l & 7;

  const float4* Wp4 = (const float4*)(W_proj + (size_t)col * HDIM);
  const float4* h4 = (const float4*)(hs + s * HDIM);
  float acc = 0.f;
#pragma unroll
  for (int i = 0; i < 16; ++i) {
    int j4 = ch * 16 + i;
    float4 hv = h4[j4];
    float4 w = Wp4[j4];
    acc = fmaf(hv.x, w.x, acc); acc = fmaf(hv.y, w.y, acc);
    acc = fmaf(hv.z, w.z, acc); acc = fmaf(hv.w, w.w, acc);
  }
#pragma unroll
  for (int m = 1; m < 8; m <<= 1) acc += __shfl_xor(acc, m);
  if (ch == 0 && s < nseg) ctx[s * CDIM + col] = acc + b_proj[col];
}

// ---------------------------------------------------------------------------
// L3: delta[s][k] = ctx[s]·W_head[k]  (b_head already applied in pass A).
// ---------------------------------------------------------------------------
__global__ __launch_bounds__(256) void delta_kernel(
    const float* __restrict__ ctx, const float* __restrict__ W_head,
    float* __restrict__ delta, int nseg) {
  __shared__ float cs[MAXSEG * CDIM];
  int t = threadIdx.x;
  {
    const float4* csrc = (const float4*)ctx;
    float4* cdst = (float4*)cs;
#pragma unroll
    for (int i = 0; i < 2; ++i) cdst[i * 256 + t] = csrc[i * 256 + t];
  }
  __syncthreads();

  int wv = t >> 6, l = t & 63;
  int k = (int)blockIdx.x * 4 + wv;
  if (k >= KCLS) return;
  int s = l >> 3, ch = l & 7;

  const float4* Wh4 = (const float4*)(W_head + (size_t)k * CDIM);
  const float4* c4 = (const float4*)(cs + s * CDIM);
  float acc = 0.f;
#pragma unroll
  for (int i = 0; i < 8; ++i) {
    int idx = ch * 8 + i;
    float4 cv = c4[idx];
    float4 w = Wh4[idx];
    acc = fmaf(cv.x, w.x, acc); acc = fmaf(cv.y, w.y, acc);
    acc = fmaf(cv.z, w.z, acc); acc = fmaf(cv.w, w.w, acc);
  }
#pragma unroll
  for (int m = 1; m < 8; m <<= 1) acc += __shfl_xor(acc, m);
  if (ch == 0 && s < nseg) delta[s * KCLS + k] = acc;
}

// ---------------------------------------------------------------------------
// Pass C: out[r][k] += delta[seg(r)][k], float4 grid-stride.
// ---------------------------------------------------------------------------
__global__ __launch_bounds__(256) void add_delta_kernel(
    float* __restrict__ out, const int* __restrict__ offset,
    const float* __restrict__ delta, int n, int nseg) {
  __shared__ float dl[MAXSEG * KCLS];
  int t = threadIdx.x;
  if (t < MAXSEG * KCLS) dl[t] = (t < nseg * KCLS) ? delta[t] : 0.f;
  __syncthreads();

  int off[MAXSEG];
#pragma unroll
  for (int q = 0; q < MAXSEG; ++q) off[q] = (q < nseg) ? offset[q] : 0x7fffffff;

  long tot = (long)n * (KCLS / 4);
  long stride = (long)gridDim.x * 256;
  for (long e4 = (long)blockIdx.x * 256 + t; e4 < tot; e4 += stride) {
    long row = e4 / 5;
    int k0 = (int)(e4 - row * 5) * 4;
    int s = 0;
#pragma unroll
    for (int q = 0; q < MAXSEG - 1; ++q) s += (row >= off[q]) ? 1 : 0;
    float4 v = ((float4*)out)[e4];
    const float* d = &dl[s * KCLS + k0];
    v.x += d[0]; v.y += d[1]; v.z += d[2]; v.w += d[3];
    ((float4*)out)[e4] = v;
  }
}

extern "C" void kernel_launch(void* const* d_in, const int* in_sizes, int n_in,
                              void* d_out, int out_size, void* d_ws, size_t ws_size,
                              hipStream_t stream) {
  const float* feat   = (const float*)d_in[0];
  const int*   offset = (const int*)d_in[1];
  const float* W_ih   = (const float*)d_in[2];
  const float* b_ih   = (const float*)d_in[3];
  // d_in[4] = W_hh : unused (h0 == 0)
  const float* b_hh   = (const float*)d_in[5];
  const float* W_proj = (const float*)d_in[6];
  const float* b_proj = (const float*)d_in[7];
  const float* W_head = (const float*)d_in[8];
  const float* b_head = (const float*)d_in[9];
  float* out = (float*)d_out;

  int n = in_sizes[0] / CDIM;
  int nseg = in_sizes[1];
  if (nseg > MAXSEG) nseg = MAXSEG;

  float* ws    = (float*)d_ws;
  float* sums  = ws;                                    // 8*256
  float* h     = ws + MAXSEG * CDIM;                    // 8*512
  float* ctx   = ws + MAXSEG * CDIM + MAXSEG * HDIM;    // 8*256
  float* delta = ctx + MAXSEG * CDIM;                   // 8*20

  hipMemsetAsync(sums, 0, MAXSEG * CDIM * sizeof(float), stream);
  fused_stream_kernel<<<2048, 256, 0, stream>>>(feat, offset, W_head, b_head,
                                                sums, out, n, nseg);
  lstm_h_kernel<<<128, 256, 0, stream>>>(sums, offset, W_ih, b_ih, b_hh, h, nseg);
  ctx_kernel<<<64, 256, 0, stream>>>(h, W_proj, b_proj, ctx, nseg);
  delta_kernel<<<5, 256, 0, stream>>>(ctx, W_head, delta, nseg);
  add_delta_kernel<<<2560, 256, 0, stream>>>(out, offset, delta, n, nseg);
}

// Round 8
// 370.611 us; speedup vs baseline: 6.5466x; 6.5466x over previous
//
#include <hip/hip_runtime.h>
#include <math.h>

#define CDIM 256
#define HDIM 512
#define KCLS 20
#define MAXSEG 8
#define TILE_R 64
#define NTHR 512
#define GRIDA 512
#define F4_TILE (TILE_R * CDIM / 4)   // 4096 float4 per tile
#define F4_THR (F4_TILE / NTHR)       // 8 float4 per thread

// Raw barrier: order LDS (lgkmcnt) but leave global loads (vmcnt) IN FLIGHT.
#define BARRIER_LDS_ONLY()                                   \
  do {                                                       \
    asm volatile("s_waitcnt lgkmcnt(0)" ::: "memory");       \
    __builtin_amdgcn_s_barrier();                            \
    __builtin_amdgcn_sched_barrier(0);                       \
  } while (0)

// ---------------------------------------------------------------------------
// Pass A (R4 structure + counted-vmcnt barriers): single read of feat.
// 64KB LDS tile (2 blocks/CU), 2-deep register staging:
//   round: issue(t+2 -> stgA); compute(t); BAR; ds_write(stgB=t+1) [auto
//          s_waitcnt vmcnt(8): stgA's newer loads stay in flight]; BAR; ...
// No vmcnt(0) drain anywhere in the loop -> HBM continuously fed.
// Swizzle: logical float4 (rr,c4) at rr*64 + (c4 ^ (rr&7)).
// Work split: all 512 thr colsum (col=t&255, 32-row half); head lane=row,
// waves 0-3 = 3 classes, waves 4-7 = 2 (W_head wave-uniform -> s_loads).
// ---------------------------------------------------------------------------
__global__ __launch_bounds__(NTHR, 4) void fused_pool_head_kernel(
    const float* __restrict__ feat, const int* __restrict__ offset,
    const float* __restrict__ W_head, const float* __restrict__ b_head,
    float* __restrict__ sums, float* __restrict__ out, int n, int nseg) {
  __shared__ float tile[TILE_R * CDIM];  // 64 KB
  float4* tile4 = (float4*)tile;
  int t = threadIdx.x;
  int lane = t & 63;
  int wv = t >> 6;

  int kb_ = (wv < 4) ? wv * 3 : 12 + (wv - 4) * 2;
  int kb = __builtin_amdgcn_readfirstlane(kb_);
  float bh0 = b_head[kb], bh1 = b_head[kb + 1];
  float bh2 = (wv < 4) ? b_head[kb + 2] : 0.f;

  int ntiles = (n + TILE_R - 1) / TILE_R;
  int nb = (int)gridDim.x;
  int t0 = (int)blockIdx.x;

  int off[MAXSEG];
#pragma unroll
  for (int q = 0; q < MAXSEG; ++q) off[q] = (q < nseg) ? offset[q] : 0x7fffffff;

  int col = t & 255;
  int rhalf = (t >> 8) * 32;
  int c4s = col >> 2, js = col & 3;
  float colacc = 0.f;
  int cur_seg = -1;

  const float4* src = (const float4*)feat;
  long lim = (long)n * (CDIM / 4);
  float4 stgA[F4_THR], stgB[F4_THR];

  auto issue = [&](float4* stg, int tl) {
    long base = (long)tl * F4_TILE;
    if (base + F4_TILE <= lim) {
#pragma unroll
      for (int i = 0; i < F4_THR; ++i) stg[i] = src[base + i * NTHR + t];
    } else {
#pragma unroll
      for (int i = 0; i < F4_THR; ++i) {
        long idx = base + i * NTHR + t;
        stg[i] = (idx < lim) ? src[idx] : make_float4(0.f, 0.f, 0.f, 0.f);
      }
    }
  };
  auto dswrite = [&](const float4* stg) {
#pragma unroll
    for (int i = 0; i < F4_THR; ++i) {
      int idx = i * NTHR + t;
      int rr = idx >> 6, c4 = idx & 63;
      tile4[rr * 64 + (c4 ^ (rr & 7))] = stg[i];
    }
  };
  auto compute = [&](int tl) {
    long r0 = (long)tl * TILE_R;
    int rows = (int)(((long)n - r0) < TILE_R ? ((long)n - r0) : TILE_R);

    // ---- (1) per-segment column sums on my 32-row half ----
    {
      int rlo = rhalf, rhi = rhalf + 32;
      if (rhi > rows) rhi = rows;
      if (rlo < rhi) {
        long ra = r0 + rlo, rb = r0 + rhi - 1;
        int s0 = 0, s1 = 0;
#pragma unroll
        for (int q = 0; q < MAXSEG - 1; ++q) {
          s0 += (ra >= off[q]) ? 1 : 0;
          s1 += (rb >= off[q]) ? 1 : 0;
        }
        if (s0 == s1) {
          if (s0 != cur_seg) {
            if (cur_seg >= 0) atomicAdd(&sums[cur_seg * CDIM + col], colacc);
            colacc = 0.f;
            cur_seg = s0;
          }
          float a = 0.f;
#pragma unroll 8
          for (int rr = rlo; rr < rhi; ++rr)
            a += tile[(rr * 64 + (c4s ^ (rr & 7))) * 4 + js];
          colacc += a;
        } else {
          for (int rr = rlo; rr < rhi; ++rr) {
            long r = r0 + rr;
            int s = 0;
#pragma unroll
            for (int q = 0; q < MAXSEG - 1; ++q) s += (r >= off[q]) ? 1 : 0;
            if (s != cur_seg) {
              if (cur_seg >= 0) atomicAdd(&sums[cur_seg * CDIM + col], colacc);
              colacc = 0.f;
              cur_seg = s;
            }
            colacc += tile[(rr * 64 + (c4s ^ (rr & 7))) * 4 + js];
          }
        }
      }
    }

    // ---- (2) head partial: out[r][kb..] = feat[r]·W_head + b_head ----
    if (lane < rows) {
      const float4* trow = tile4 + lane * 64;
      int l7 = lane & 7;
      if (wv < 4) {
        float a0 = bh0, a1 = bh1, a2 = bh2;
        const float* w0 = W_head + (size_t)(kb + 0) * CDIM;
        const float* w1 = W_head + (size_t)(kb + 1) * CDIM;
        const float* w2 = W_head + (size_t)(kb + 2) * CDIM;
#pragma unroll 4
        for (int c4 = 0; c4 < 64; ++c4) {
          float4 f = trow[c4 ^ l7];
          int cb = c4 * 4;
          a0 = fmaf(f.x, w0[cb], a0);   a1 = fmaf(f.x, w1[cb], a1);   a2 = fmaf(f.x, w2[cb], a2);
          a0 = fmaf(f.y, w0[cb+1], a0); a1 = fmaf(f.y, w1[cb+1], a1); a2 = fmaf(f.y, w2[cb+1], a2);
          a0 = fmaf(f.z, w0[cb+2], a0); a1 = fmaf(f.z, w1[cb+2], a1); a2 = fmaf(f.z, w2[cb+2], a2);
          a0 = fmaf(f.w, w0[cb+3], a0); a1 = fmaf(f.w, w1[cb+3], a1); a2 = fmaf(f.w, w2[cb+3], a2);
        }
        float* orow = out + (r0 + lane) * KCLS + kb;
        orow[0] = a0; orow[1] = a1; orow[2] = a2;
      } else {
        float a0 = bh0, a1 = bh1;
        const float* w0 = W_head + (size_t)(kb + 0) * CDIM;
        const float* w1 = W_head + (size_t)(kb + 1) * CDIM;
#pragma unroll 4
        for (int c4 = 0; c4 < 64; ++c4) {
          float4 f = trow[c4 ^ l7];
          int cb = c4 * 4;
          a0 = fmaf(f.x, w0[cb], a0);   a1 = fmaf(f.x, w1[cb], a1);
          a0 = fmaf(f.y, w0[cb+1], a0); a1 = fmaf(f.y, w1[cb+1], a1);
          a0 = fmaf(f.z, w0[cb+2], a0); a1 = fmaf(f.z, w1[cb+2], a1);
          a0 = fmaf(f.w, w0[cb+3], a0); a1 = fmaf(f.w, w1[cb+3], a1);
        }
        float* orow = out + (r0 + lane) * KCLS + kb;
        orow[0] = a0; orow[1] = a1;
      }
    }
  };

  if (t0 < ntiles) {
    // ---- prologue: stage t0 and t0+nb; write t0 into LDS ----
    issue(stgA, t0);
    issue(stgB, t0 + nb < ntiles ? t0 + nb : t0);
    dswrite(stgA);                 // auto vmcnt wait for stgA only
    BARRIER_LDS_ONLY();

    for (int tl = t0; tl < ntiles; tl += 2 * nb) {
      int tA2 = tl + 2 * nb;
      if (tA2 < ntiles) issue(stgA, tA2);   // in flight across this round
      compute(tl);
      BARRIER_LDS_ONLY();                    // readers done (no vmcnt drain)
      int tB = tl + nb;
      if (tB < ntiles) {
        dswrite(stgB);                       // auto s_waitcnt vmcnt(8)
        BARRIER_LDS_ONLY();                  // writes visible
        int tB2 = tl + 3 * nb;
        if (tB2 < ntiles) issue(stgB, tB2);
        compute(tB);
        BARRIER_LDS_ONLY();
        if (tA2 < ntiles) {
          dswrite(stgA);
          BARRIER_LDS_ONLY();
        }
      }
    }
    if (cur_seg >= 0) atomicAdd(&sums[cur_seg * CDIM + col], colacc);
  }
}

// ---------------------------------------------------------------------------
// L1: h[s][j], wave-task = gate column j; coalesced W_ih float4 rows;
// 3-step shfl_xor reduce within 8-lane seg groups.
// ---------------------------------------------------------------------------
__global__ __launch_bounds__(256) void lstm_h_kernel(
    const float* __restrict__ sums, const int* __restrict__ offset,
    const float* __restrict__ W_ih, const float* __restrict__ b_ih,
    const float* __restrict__ b_hh, float* __restrict__ h, int nseg) {
  __shared__ float pooled[MAXSEG * CDIM];
  int t = threadIdx.x;
  {
    int prev = 0;
    for (int s = 0; s < MAXSEG; ++s) {
      int cur = (s < nseg) ? offset[s] : prev;
      float cnt = (float)(cur - prev);
      float inv = (cnt > 0.f) ? 1.f / cnt : 0.f;
      pooled[s * CDIM + t] = sums[s * CDIM + t] * inv;
      prev = cur;
    }
  }
  __syncthreads();

  int wv = t >> 6, l = t & 63;
  int j = (int)blockIdx.x * 4 + wv;
  int s = l >> 3, ch = l & 7;

  const float4* Wi4 = (const float4*)(W_ih + (size_t)(0 * HDIM + j) * CDIM);
  const float4* Wg4 = (const float4*)(W_ih + (size_t)(2 * HDIM + j) * CDIM);
  const float4* Wo4 = (const float4*)(W_ih + (size_t)(3 * HDIM + j) * CDIM);
  const float4* p4 = (const float4*)(pooled + s * CDIM);

  float di = 0.f, dg = 0.f, dd = 0.f;
#pragma unroll
  for (int i = 0; i < 8; ++i) {
    int c4 = ch * 8 + i;
    float4 p = p4[c4];
    float4 wi = Wi4[c4], wg = Wg4[c4], wo = Wo4[c4];
    di = fmaf(p.x, wi.x, di); di = fmaf(p.y, wi.y, di);
    di = fmaf(p.z, wi.z, di); di = fmaf(p.w, wi.w, di);
    dg = fmaf(p.x, wg.x, dg); dg = fmaf(p.y, wg.y, dg);
    dg = fmaf(p.z, wg.z, dg); dg = fmaf(p.w, wg.w, dg);
    dd = fmaf(p.x, wo.x, dd); dd = fmaf(p.y, wo.y, dd);
    dd = fmaf(p.z, wo.z, dd); dd = fmaf(p.w, wo.w, dd);
  }
#pragma unroll
  for (int m = 1; m < 8; m <<= 1) {
    di += __shfl_xor(di, m);
    dg += __shfl_xor(dg, m);
    dd += __shfl_xor(dd, m);
  }
  if (ch == 0 && s < nseg) {
    di += b_ih[j] + b_hh[j];
    dg += b_ih[2 * HDIM + j] + b_hh[2 * HDIM + j];
    dd += b_ih[3 * HDIM + j] + b_hh[3 * HDIM + j];
    float ig = 1.f / (1.f + expf(-di));
    float gg = tanhf(dg);
    float og = 1.f / (1.f + expf(-dd));
    h[(size_t)s * HDIM + j] = og * tanhf(ig * gg);
  }
}

// ---------------------------------------------------------------------------
// L2: ctx[s][col] = b_proj[col] + h[s]·W_proj[col].
// ---------------------------------------------------------------------------
__global__ __launch_bounds__(256) void ctx_kernel(
    const float* __restrict__ h, const float* __restrict__ W_proj,
    const float* __restrict__ b_proj, float* __restrict__ ctx, int nseg) {
  __shared__ float hs[MAXSEG * HDIM];
  int t = threadIdx.x;
  {
    const float4* hsrc = (const float4*)h;
    float4* hdst = (float4*)hs;
#pragma unroll
    for (int i = 0; i < 4; ++i) hdst[i * 256 + t] = hsrc[i * 256 + t];
  }
  __syncthreads();

  int wv = t >> 6, l = t & 63;
  int col = (int)blockIdx.x * 4 + wv;
  int s = l >> 3, ch = l & 7;

  const float4* Wp4 = (const float4*)(W_proj + (size_t)col * HDIM);
  const float4* h4 = (const float4*)(hs + s * HDIM);
  float acc = 0.f;
#pragma unroll
  for (int i = 0; i < 16; ++i) {
    int j4 = ch * 16 + i;
    float4 hv = h4[j4];
    float4 w = Wp4[j4];
    acc = fmaf(hv.x, w.x, acc); acc = fmaf(hv.y, w.y, acc);
    acc = fmaf(hv.z, w.z, acc); acc = fmaf(hv.w, w.w, acc);
  }
#pragma unroll
  for (int m = 1; m < 8; m <<= 1) acc += __shfl_xor(acc, m);
  if (ch == 0 && s < nseg) ctx[s * CDIM + col] = acc + b_proj[col];
}

// ---------------------------------------------------------------------------
// L3: delta[s][k] = ctx[s]·W_head[k]  (b_head already applied in pass A).
// ---------------------------------------------------------------------------
__global__ __launch_bounds__(256) void delta_kernel(
    const float* __restrict__ ctx, const float* __restrict__ W_head,
    float* __restrict__ delta, int nseg) {
  __shared__ float cs[MAXSEG * CDIM];
  int t = threadIdx.x;
  {
    const float4* csrc = (const float4*)ctx;
    float4* cdst = (float4*)cs;
#pragma unroll
    for (int i = 0; i < 2; ++i) cdst[i * 256 + t] = csrc[i * 256 + t];
  }
  __syncthreads();

  int wv = t >> 6, l = t & 63;
  int k = (int)blockIdx.x * 4 + wv;
  if (k >= KCLS) return;
  int s = l >> 3, ch = l & 7;

  const float4* Wh4 = (const float4*)(W_head + (size_t)k * CDIM);
  const float4* c4 = (const float4*)(cs + s * CDIM);
  float acc = 0.f;
#pragma unroll
  for (int i = 0; i < 8; ++i) {
    int idx = ch * 8 + i;
    float4 cv = c4[idx];
    float4 w = Wh4[idx];
    acc = fmaf(cv.x, w.x, acc); acc = fmaf(cv.y, w.y, acc);
    acc = fmaf(cv.z, w.z, acc); acc = fmaf(cv.w, w.w, acc);
  }
#pragma unroll
  for (int m = 1; m < 8; m <<= 1) acc += __shfl_xor(acc, m);
  if (ch == 0 && s < nseg) delta[s * KCLS + k] = acc;
}

// ---------------------------------------------------------------------------
// Pass C: out[r][k] += delta[seg(r)][k], float4 grid-stride.
// ---------------------------------------------------------------------------
__global__ __launch_bounds__(256) void add_delta_kernel(
    float* __restrict__ out, const int* __restrict__ offset,
    const float* __restrict__ delta, int n, int nseg) {
  __shared__ float dl[MAXSEG * KCLS];
  int t = threadIdx.x;
  if (t < MAXSEG * KCLS) dl[t] = (t < nseg * KCLS) ? delta[t] : 0.f;
  __syncthreads();

  int off[MAXSEG];
#pragma unroll
  for (int q = 0; q < MAXSEG; ++q) off[q] = (q < nseg) ? offset[q] : 0x7fffffff;

  long tot = (long)n * (KCLS / 4);
  long stride = (long)gridDim.x * 256;
  for (long e4 = (long)blockIdx.x * 256 + t; e4 < tot; e4 += stride) {
    long row = e4 / 5;
    int k0 = (int)(e4 - row * 5) * 4;
    int s = 0;
#pragma unroll
    for (int q = 0; q < MAXSEG - 1; ++q) s += (row >= off[q]) ? 1 : 0;
    float4 v = ((float4*)out)[e4];
    const float* d = &dl[s * KCLS + k0];
    v.x += d[0]; v.y += d[1]; v.z += d[2]; v.w += d[3];
    ((float4*)out)[e4] = v;
  }
}

extern "C" void kernel_launch(void* const* d_in, const int* in_sizes, int n_in,
                              void* d_out, int out_size, void* d_ws, size_t ws_size,
                              hipStream_t stream) {
  const float* feat   = (const float*)d_in[0];
  const int*   offset = (const int*)d_in[1];
  const float* W_ih   = (const float*)d_in[2];
  const float* b_ih   = (const float*)d_in[3];
  // d_in[4] = W_hh : unused (h0 == 0)
  const float* b_hh   = (const float*)d_in[5];
  const float* W_proj = (const float*)d_in[6];
  const float* b_proj = (const float*)d_in[7];
  const float* W_head = (const float*)d_in[8];
  const float* b_head = (const float*)d_in[9];
  float* out = (float*)d_out;

  int n = in_sizes[0] / CDIM;
  int nseg = in_sizes[1];
  if (nseg > MAXSEG) nseg = MAXSEG;

  float* ws    = (float*)d_ws;
  float* sums  = ws;                                    // 8*256
  float* h     = ws + MAXSEG * CDIM;                    // 8*512
  float* ctx   = ws + MAXSEG * CDIM + MAXSEG * HDIM;    // 8*256
  float* delta = ctx + MAXSEG * CDIM;                   // 8*20

  hipMemsetAsync(sums, 0, MAXSEG * CDIM * sizeof(float), stream);
  fused_pool_head_kernel<<<GRIDA, NTHR, 0, stream>>>(feat, offset, W_head, b_head,
                                                     sums, out, n, nseg);
  lstm_h_kernel<<<128, 256, 0, stream>>>(sums, offset, W_ih, b_ih, b_hh, h, nseg);
  ctx_kernel<<<64, 256, 0, stream>>>(h, W_proj, b_proj, ctx, nseg);
  delta_kernel<<<5, 256, 0, stream>>>(ctx, W_head, delta, nseg);
  add_delta_kernel<<<2560, 256, 0, stream>>>(out, offset, delta, n, nseg);
}